// Round 1
// baseline (295.994 us; speedup 1.0000x reference)
//
#include <hip/hip_runtime.h>

namespace {

constexpr int B_ = 256, C_ = 3, H_ = 224, W_ = 224;
constexpr int HW   = H_ * W_;     // 50176
constexpr int HW4  = HW / 4;      // 12544 float4 groups per plane
constexpr int W4   = W_ / 4;      // 56 float4 groups per row
constexpr int BLK  = 256;
constexpr int BLOCKS_PER_IMG = HW4 / BLK;  // 49 (exact)

__device__ __forceinline__ float4 rev4(float4 v) {
    return make_float4(v.w, v.z, v.y, v.x);
}
__device__ __forceinline__ float clip1(float v) {
    return fminf(fmaxf(v, -2.5f), 2.5f);
}

// ---------------------------------------------------------------------------
// Pass 1: raw per-(b,c) plane means of the ORIGINAL x.
// (flip doesn't change a mean; gray/brightness handled analytically in pass 2)
// ---------------------------------------------------------------------------
__global__ __launch_bounds__(BLK) void mean_kernel(const float* __restrict__ x,
                                                   float* __restrict__ means) {
    const int plane = blockIdx.x;  // b*3 + c, 0..767
    const float4* p = reinterpret_cast<const float4*>(x) + (size_t)plane * HW4;

    float s = 0.f;
#pragma unroll 4
    for (int i = threadIdx.x; i < HW4; i += BLK) {
        float4 v = p[i];
        s += (v.x + v.y) + (v.z + v.w);
    }
    // wave-64 butterfly
#pragma unroll
    for (int off = 32; off > 0; off >>= 1) s += __shfl_down(s, off, 64);

    __shared__ float partial[BLK / 64];
    const int lane = threadIdx.x & 63;
    const int wv   = threadIdx.x >> 6;
    if (lane == 0) partial[wv] = s;
    __syncthreads();
    if (threadIdx.x == 0) {
        float t = (partial[0] + partial[1]) + (partial[2] + partial[3]);
        means[plane] = t * (1.0f / HW);
    }
}

// ---------------------------------------------------------------------------
// Pass 2: fused flip + gray + brightness + contrast + clip.
// One thread = 4 pixels (one float4 group), all 3 channels.
// out_c = clip(sel_c * A + B_c)
//   A   = brightness * (apply ? cf : 1)
//   B_c = apply ? brightness * mean_eff_c * (1 - cf) : 0
//   mean_eff_c = gray ? dot(gw, raw_means) : raw_means[c]
// ---------------------------------------------------------------------------
__global__ __launch_bounds__(BLK) void xform_kernel(
    const float* __restrict__ x,
    const float* __restrict__ brightness,
    const float* __restrict__ cfac,
    const int*  __restrict__ flip_mask,
    const int*  __restrict__ gray_mask,
    const int*  __restrict__ contrast_apply,
    const float* __restrict__ means,
    float* __restrict__ out) {

    const int b = blockIdx.x / BLOCKS_PER_IMG;                    // uniform per block
    const int p = (blockIdx.x % BLOCKS_PER_IMG) * BLK + threadIdx.x;  // 0..12543
    const int h  = p / W4;
    const int w4 = p % W4;

    const bool fl = flip_mask[b] != 0;
    const bool gr = gray_mask[b] != 0;
    const bool ca = contrast_apply[b] != 0;
    const float br = brightness[b];
    const float cf = cfac[b];

    const float m0 = means[b * 3 + 0];
    const float m1 = means[b * 3 + 1];
    const float m2 = means[b * 3 + 2];
    const float gmean = 0.2989f * m0 + 0.587f * m1 + 0.114f * m2;

    const float A = br * (ca ? cf : 1.f);
    float B0 = 0.f, B1 = 0.f, B2 = 0.f;
    if (ca) {
        const float k = br * (1.f - cf);
        if (gr) { B0 = B1 = B2 = k * gmean; }
        else    { B0 = k * m0; B1 = k * m1; B2 = k * m2; }
    }

    const int srcw4 = fl ? (W4 - 1 - w4) : w4;
    const size_t src = (size_t)b * (C_ * HW) + (size_t)h * W_ + (size_t)srcw4 * 4;

    float4 r = *reinterpret_cast<const float4*>(x + src);
    float4 g = *reinterpret_cast<const float4*>(x + src + HW);
    float4 bl = *reinterpret_cast<const float4*>(x + src + 2 * HW);
    if (fl) { r = rev4(r); g = rev4(g); bl = rev4(bl); }

    if (gr) {
        float4 gy;
        gy.x = 0.2989f * r.x + 0.587f * g.x + 0.114f * bl.x;
        gy.y = 0.2989f * r.y + 0.587f * g.y + 0.114f * bl.y;
        gy.z = 0.2989f * r.z + 0.587f * g.z + 0.114f * bl.z;
        gy.w = 0.2989f * r.w + 0.587f * g.w + 0.114f * bl.w;
        r = gy; g = gy; bl = gy;
    }

    float4 o0, o1, o2;
    o0.x = clip1(r.x * A + B0);  o0.y = clip1(r.y * A + B0);
    o0.z = clip1(r.z * A + B0);  o0.w = clip1(r.w * A + B0);
    o1.x = clip1(g.x * A + B1);  o1.y = clip1(g.y * A + B1);
    o1.z = clip1(g.z * A + B1);  o1.w = clip1(g.w * A + B1);
    o2.x = clip1(bl.x * A + B2); o2.y = clip1(bl.y * A + B2);
    o2.z = clip1(bl.z * A + B2); o2.w = clip1(bl.w * A + B2);

    const size_t dst = (size_t)b * (C_ * HW) + (size_t)h * W_ + (size_t)w4 * 4;
    *reinterpret_cast<float4*>(out + dst)          = o0;
    *reinterpret_cast<float4*>(out + dst + HW)     = o1;
    *reinterpret_cast<float4*>(out + dst + 2 * HW) = o2;
}

}  // namespace

extern "C" void kernel_launch(void* const* d_in, const int* in_sizes, int n_in,
                              void* d_out, int out_size, void* d_ws, size_t ws_size,
                              hipStream_t stream) {
    const float* x          = (const float*)d_in[0];
    const float* brightness = (const float*)d_in[1];
    const float* cfac       = (const float*)d_in[2];
    const int*   flip_mask  = (const int*)d_in[3];
    const int*   gray_mask  = (const int*)d_in[4];
    const int*   contrast_a = (const int*)d_in[5];
    float* out   = (float*)d_out;
    float* means = (float*)d_ws;  // 768 floats

    mean_kernel<<<B_ * C_, BLK, 0, stream>>>(x, means);
    xform_kernel<<<B_ * BLOCKS_PER_IMG, BLK, 0, stream>>>(
        x, brightness, cfac, flip_mask, gray_mask, contrast_a, means, out);
}

// Round 2
// 276.476 us; speedup vs baseline: 1.0706x; 1.0706x over previous
//
#include <hip/hip_runtime.h>

namespace {

constexpr int B_ = 256, C_ = 3, H_ = 224, W_ = 224;
constexpr int HW   = H_ * W_;     // 50176
constexpr int HW4  = HW / 4;      // 12544 float4 groups per plane
constexpr int W4   = W_ / 4;      // 56 float4 groups per row
constexpr int BLK  = 256;
constexpr int BLOCKS_PER_IMG = HW4 / BLK;  // 49 (exact)

using f4 = __attribute__((ext_vector_type(4))) float;

__device__ __forceinline__ f4 rev4(f4 v) {
    f4 r; r.x = v.w; r.y = v.z; r.z = v.y; r.w = v.x; return r;
}
__device__ __forceinline__ float clip1(float v) {
    return fminf(fmaxf(v, -2.5f), 2.5f);
}

// ---------------------------------------------------------------------------
// Pass 1: raw per-(b,c) plane means of the ORIGINAL x — but ONLY for images
// where contrast will actually be applied (the mean is unused otherwise).
// Normal (cached) loads: we want x resident in L3 for pass 2.
// ---------------------------------------------------------------------------
__global__ __launch_bounds__(BLK) void mean_kernel(const float* __restrict__ x,
                                                   const int* __restrict__ contrast_apply,
                                                   float* __restrict__ means) {
    const int plane = blockIdx.x;  // b*3 + c, 0..767
    if (contrast_apply[plane / 3] == 0) {
        if (threadIdx.x == 0) means[plane] = 0.f;  // hygiene: never leave poison
        return;
    }
    const f4* p = reinterpret_cast<const f4*>(x) + (size_t)plane * HW4;

    float s = 0.f;
#pragma unroll 4
    for (int i = threadIdx.x; i < HW4; i += BLK) {
        f4 v = p[i];
        s += (v.x + v.y) + (v.z + v.w);
    }
    // wave-64 butterfly
#pragma unroll
    for (int off = 32; off > 0; off >>= 1) s += __shfl_down(s, off, 64);

    __shared__ float partial[BLK / 64];
    const int lane = threadIdx.x & 63;
    const int wv   = threadIdx.x >> 6;
    if (lane == 0) partial[wv] = s;
    __syncthreads();
    if (threadIdx.x == 0) {
        float t = (partial[0] + partial[1]) + (partial[2] + partial[3]);
        means[plane] = t * (1.0f / HW);
    }
}

// ---------------------------------------------------------------------------
// Pass 2: fused flip + gray + brightness + contrast + clip.
// One thread = 4 pixels (one float4 group), all 3 channels.
// out_c = clip(sel_c * A + B_c)
//   A   = brightness * (apply ? cf : 1)
//   B_c = apply ? brightness * mean_eff_c * (1 - cf) : 0
//   mean_eff_c = gray ? dot(gw, raw_means) : raw_means[c]
// Non-temporal: x-read is the last use, out is never re-read.
// ---------------------------------------------------------------------------
__global__ __launch_bounds__(BLK) void xform_kernel(
    const float* __restrict__ x,
    const float* __restrict__ brightness,
    const float* __restrict__ cfac,
    const int*  __restrict__ flip_mask,
    const int*  __restrict__ gray_mask,
    const int*  __restrict__ contrast_apply,
    const float* __restrict__ means,
    float* __restrict__ out) {

    const int b = blockIdx.x / BLOCKS_PER_IMG;                        // uniform per block
    const int p = (blockIdx.x % BLOCKS_PER_IMG) * BLK + threadIdx.x;  // 0..12543
    const int h  = p / W4;
    const int w4 = p % W4;

    const bool fl = flip_mask[b] != 0;
    const bool gr = gray_mask[b] != 0;
    const bool ca = contrast_apply[b] != 0;
    const float br = brightness[b];
    const float cf = cfac[b];

    const float m0 = means[b * 3 + 0];
    const float m1 = means[b * 3 + 1];
    const float m2 = means[b * 3 + 2];
    const float gmean = 0.2989f * m0 + 0.587f * m1 + 0.114f * m2;

    const float A = br * (ca ? cf : 1.f);
    float B0 = 0.f, B1 = 0.f, B2 = 0.f;
    if (ca) {
        const float k = br * (1.f - cf);
        if (gr) { B0 = B1 = B2 = k * gmean; }
        else    { B0 = k * m0; B1 = k * m1; B2 = k * m2; }
    }

    const int srcw4 = fl ? (W4 - 1 - w4) : w4;
    const size_t src = (size_t)b * (C_ * HW) + (size_t)h * W_ + (size_t)srcw4 * 4;

    f4 r  = __builtin_nontemporal_load(reinterpret_cast<const f4*>(x + src));
    f4 g  = __builtin_nontemporal_load(reinterpret_cast<const f4*>(x + src + HW));
    f4 bl = __builtin_nontemporal_load(reinterpret_cast<const f4*>(x + src + 2 * HW));
    if (fl) { r = rev4(r); g = rev4(g); bl = rev4(bl); }

    if (gr) {
        f4 gy;
        gy.x = 0.2989f * r.x + 0.587f * g.x + 0.114f * bl.x;
        gy.y = 0.2989f * r.y + 0.587f * g.y + 0.114f * bl.y;
        gy.z = 0.2989f * r.z + 0.587f * g.z + 0.114f * bl.z;
        gy.w = 0.2989f * r.w + 0.587f * g.w + 0.114f * bl.w;
        r = gy; g = gy; bl = gy;
    }

    f4 o0, o1, o2;
    o0.x = clip1(r.x * A + B0);  o0.y = clip1(r.y * A + B0);
    o0.z = clip1(r.z * A + B0);  o0.w = clip1(r.w * A + B0);
    o1.x = clip1(g.x * A + B1);  o1.y = clip1(g.y * A + B1);
    o1.z = clip1(g.z * A + B1);  o1.w = clip1(g.w * A + B1);
    o2.x = clip1(bl.x * A + B2); o2.y = clip1(bl.y * A + B2);
    o2.z = clip1(bl.z * A + B2); o2.w = clip1(bl.w * A + B2);

    const size_t dst = (size_t)b * (C_ * HW) + (size_t)h * W_ + (size_t)w4 * 4;
    __builtin_nontemporal_store(o0, reinterpret_cast<f4*>(out + dst));
    __builtin_nontemporal_store(o1, reinterpret_cast<f4*>(out + dst + HW));
    __builtin_nontemporal_store(o2, reinterpret_cast<f4*>(out + dst + 2 * HW));
}

}  // namespace

extern "C" void kernel_launch(void* const* d_in, const int* in_sizes, int n_in,
                              void* d_out, int out_size, void* d_ws, size_t ws_size,
                              hipStream_t stream) {
    const float* x          = (const float*)d_in[0];
    const float* brightness = (const float*)d_in[1];
    const float* cfac       = (const float*)d_in[2];
    const int*   flip_mask  = (const int*)d_in[3];
    const int*   gray_mask  = (const int*)d_in[4];
    const int*   contrast_a = (const int*)d_in[5];
    float* out   = (float*)d_out;
    float* means = (float*)d_ws;  // 768 floats

    mean_kernel<<<B_ * C_, BLK, 0, stream>>>(x, contrast_a, means);
    xform_kernel<<<B_ * BLOCKS_PER_IMG, BLK, 0, stream>>>(
        x, brightness, cfac, flip_mask, gray_mask, contrast_a, means, out);
}